// Round 1
// baseline (72.705 us; speedup 1.0000x reference)
//
#include <hip/hip_runtime.h>

#define NUM_F 256
#define DIM 128
#define LN_EPS 1e-5f

// Each wave handles TWO rows (tokens): lanes 0-31 -> row 2p, lanes 32-63 -> row 2p+1.
// Each lane owns a float4 (4 of the 128 elements). Reduction via shfl_xor offsets
// 1..16 stays within each 32-lane half, so both rows reduce concurrently.
__global__ __launch_bounds__(256) void FeatureTokenizer_kernel(
    const float* __restrict__ x,      // (B, F)
    const float* __restrict__ W,      // (F, D)
    const float* __restrict__ bvec,   // (F, D)
    const float* __restrict__ E,      // (F, D)
    const float* __restrict__ gamma,  // (D,)
    const float* __restrict__ beta,   // (D,)
    float* __restrict__ out,          // (B, F, D)
    int nrows)                        // B*F (even)
{
    const int lane   = threadIdx.x & 63;
    const int half   = lane >> 5;        // 0 or 1: which row of the pair
    const int lane32 = lane & 31;        // position within the row
    const int waveInBlk = threadIdx.x >> 6;
    const int wavesPerBlk = blockDim.x >> 6;
    const int gwave  = blockIdx.x * wavesPerBlk + waveInBlk;
    const int nwaves = gridDim.x * wavesPerBlk;
    const int npairs = nrows >> 1;

    const int dbase = lane32 * 4;        // element offset within the row
    const float4 g  = *reinterpret_cast<const float4*>(gamma + dbase);
    const float4 bt = *reinterpret_cast<const float4*>(beta  + dbase);

    for (int p = gwave; p < npairs; p += nwaves) {
        const int row = 2 * p + half;
        const int f   = row & (NUM_F - 1);

        // x is (B, F) row-major: linear index == row. Uniform within each half.
        const float xv = x[row];

        const float4 w  = *reinterpret_cast<const float4*>(W    + f * DIM + dbase);
        const float4 bv = *reinterpret_cast<const float4*>(bvec + f * DIM + dbase);
        const float4 ev = *reinterpret_cast<const float4*>(E    + f * DIM + dbase);

        float t0 = fmaf(xv, w.x, bv.x + ev.x);
        float t1 = fmaf(xv, w.y, bv.y + ev.y);
        float t2 = fmaf(xv, w.z, bv.z + ev.z);
        float t3 = fmaf(xv, w.w, bv.w + ev.w);

        float s  = (t0 + t1) + (t2 + t3);
        float ss = (t0 * t0 + t1 * t1) + (t2 * t2 + t3 * t3);
        #pragma unroll
        for (int off = 16; off >= 1; off >>= 1) {
            s  += __shfl_xor(s,  off, 64);
            ss += __shfl_xor(ss, off, 64);
        }

        const float mean = s * (1.0f / DIM);
        const float var  = ss * (1.0f / DIM) - mean * mean;
        const float rstd = rsqrtf(var + LN_EPS);

        float4 o;
        o.x = (t0 - mean) * rstd * g.x + bt.x;
        o.y = (t1 - mean) * rstd * g.y + bt.y;
        o.z = (t2 - mean) * rstd * g.z + bt.z;
        o.w = (t3 - mean) * rstd * g.w + bt.w;

        *reinterpret_cast<float4*>(out + (size_t)row * DIM + dbase) = o;
    }
}

extern "C" void kernel_launch(void* const* d_in, const int* in_sizes, int n_in,
                              void* d_out, int out_size, void* d_ws, size_t ws_size,
                              hipStream_t stream) {
    const float* x     = (const float*)d_in[0];   // (B, F)
    const float* W     = (const float*)d_in[1];   // (F, D)
    const float* bvec  = (const float*)d_in[2];   // (F, D)
    const float* E     = (const float*)d_in[3];   // (F, D)
    const float* gamma = (const float*)d_in[4];   // (D,)
    const float* beta  = (const float*)d_in[5];   // (D,)
    float* out = (float*)d_out;

    const int B = in_sizes[0] / NUM_F;
    const int nrows = B * NUM_F;                  // 524288
    const int npairs = nrows / 2;

    const int block = 256;                        // 4 waves/block
    const int wavesPerBlk = block / 64;
    int grid = (npairs + wavesPerBlk - 1) / wavesPerBlk;
    if (grid > 2048) grid = 2048;                 // grid-stride the rest

    FeatureTokenizer_kernel<<<grid, block, 0, stream>>>(
        x, W, bvec, E, gamma, beta, out, nrows);
}

// Round 2
// 57.065 us; speedup vs baseline: 1.2741x; 1.2741x over previous
//
#include <hip/hip_runtime.h>

#define NUM_F 256
#define DIM 128
#define LN_EPS 1e-5f

// ---------------------------------------------------------------------------
// Pass 1 (tiny, one wave per feature): compute c = b + E, and the 5 per-feature
// LayerNorm closed-form constants:
//   mean(t)  = x*(Sw/128) + (Sc/128)
//   E[t^2]   = x^2*(Sww/128) + x*(2*Swc/128) + (Scc/128)
//   var      = E[t^2] - mean^2
// packed as m4 = {Sw/128, Sc/128, 2*Swc/128, Sww/128}, a0 = Scc/128.
// ---------------------------------------------------------------------------
__global__ __launch_bounds__(64) void ft_precompute_kernel(
    const float* __restrict__ W,     // (F, D)
    const float* __restrict__ bvec,  // (F, D)
    const float* __restrict__ E,     // (F, D)
    float*  __restrict__ c,          // (F, D) out
    float4* __restrict__ m4,         // (F,) out
    float*  __restrict__ a0)         // (F,) out
{
    const int f = blockIdx.x;
    const int l = threadIdx.x;           // 0..63
    const int base = f * DIM;

    const float w0 = W[base + l];
    const float w1 = W[base + l + 64];
    const float c0 = bvec[base + l]      + E[base + l];
    const float c1 = bvec[base + l + 64] + E[base + l + 64];
    c[base + l]      = c0;
    c[base + l + 64] = c1;

    float sw  = w0 + w1;
    float sc  = c0 + c1;
    float sww = w0 * w0 + w1 * w1;
    float swc = w0 * c0 + w1 * c1;
    float scc = c0 * c0 + c1 * c1;
    #pragma unroll
    for (int off = 32; off >= 1; off >>= 1) {
        sw  += __shfl_xor(sw,  off, 64);
        sc  += __shfl_xor(sc,  off, 64);
        sww += __shfl_xor(sww, off, 64);
        swc += __shfl_xor(swc, off, 64);
        scc += __shfl_xor(scc, off, 64);
    }
    if (l == 0) {
        const float inv = 1.0f / (float)DIM;
        m4[f] = make_float4(sw * inv, sc * inv, 2.0f * swc * inv, sww * inv);
        a0[f] = scc * inv;
    }
}

// ---------------------------------------------------------------------------
// Pass 2: pure streaming. Lanes 0-31 -> row 2p, lanes 32-63 -> row 2p+1; each
// lane owns a float4 of the 128-dim row. Because the grid-stride row step
// (2*nwaves = 16384) is a multiple of NUM_F, each wave's feature f is CONSTANT
// across iterations -> W/c/gamma/beta/params hoisted out of the loop.
// Loop body: 1 scalar x load -> ~27 VALU -> one float4 store. No shuffles.
// ---------------------------------------------------------------------------
__global__ __launch_bounds__(256) void ft_main_kernel(
    const float*  __restrict__ x,     // (B, F)
    const float*  __restrict__ W,     // (F, D)
    const float*  __restrict__ c,     // (F, D)
    const float4* __restrict__ m4p,   // (F,)
    const float*  __restrict__ a0p,   // (F,)
    const float*  __restrict__ gamma, // (D,)
    const float*  __restrict__ beta,  // (D,)
    float* __restrict__ out,          // (B, F, D)
    int nrows)
{
    const int lane   = threadIdx.x & 63;
    const int half   = lane >> 5;
    const int lane32 = lane & 31;
    const int waveInBlk   = threadIdx.x >> 6;
    const int wavesPerBlk = blockDim.x >> 6;
    const int gwave  = blockIdx.x * wavesPerBlk + waveInBlk;
    const int nwaves = gridDim.x * wavesPerBlk;

    const int row0 = 2 * gwave + half;
    const int rstep = 2 * nwaves;              // multiple of NUM_F by construction
    const int f     = row0 & (NUM_F - 1);      // constant per wave
    const int dbase = lane32 * 4;

    const float4 w  = *reinterpret_cast<const float4*>(W + f * DIM + dbase);
    const float4 cv = *reinterpret_cast<const float4*>(c + f * DIM + dbase);
    const float4 g  = *reinterpret_cast<const float4*>(gamma + dbase);
    const float4 bt = *reinterpret_cast<const float4*>(beta  + dbase);
    const float4 m  = m4p[f];
    const float  a0 = a0p[f];

    for (int row = row0; row < nrows; row += rstep) {
        const float xv = x[row];

        const float mean = fmaf(xv, m.x, m.y);
        const float exx  = fmaf(xv * xv, m.w, fmaf(xv, m.z, a0));
        const float var  = fmaf(-mean, mean, exx);
        const float rstd = rsqrtf(var + LN_EPS);

        float4 o;
        const float t0 = fmaf(xv, w.x, cv.x);
        const float t1 = fmaf(xv, w.y, cv.y);
        const float t2 = fmaf(xv, w.z, cv.z);
        const float t3 = fmaf(xv, w.w, cv.w);
        o.x = fmaf((t0 - mean) * rstd, g.x, bt.x);
        o.y = fmaf((t1 - mean) * rstd, g.y, bt.y);
        o.z = fmaf((t2 - mean) * rstd, g.z, bt.z);
        o.w = fmaf((t3 - mean) * rstd, g.w, bt.w);

        *reinterpret_cast<float4*>(out + (size_t)row * DIM + dbase) = o;
    }
}

extern "C" void kernel_launch(void* const* d_in, const int* in_sizes, int n_in,
                              void* d_out, int out_size, void* d_ws, size_t ws_size,
                              hipStream_t stream) {
    const float* x     = (const float*)d_in[0];   // (B, F)
    const float* W     = (const float*)d_in[1];   // (F, D)
    const float* bvec  = (const float*)d_in[2];   // (F, D)
    const float* E     = (const float*)d_in[3];   // (F, D)
    const float* gamma = (const float*)d_in[4];   // (D,)
    const float* beta  = (const float*)d_in[5];   // (D,)
    float* out = (float*)d_out;

    const int B = in_sizes[0] / NUM_F;
    const int nrows = B * NUM_F;

    // workspace layout: c (F*D floats) | m4 (F float4) | a0 (F floats)
    float*  c  = (float*)d_ws;
    float4* m4 = (float4*)((char*)d_ws + (size_t)NUM_F * DIM * sizeof(float));
    float*  a0 = (float*)((char*)m4 + (size_t)NUM_F * sizeof(float4));

    ft_precompute_kernel<<<NUM_F, 64, 0, stream>>>(W, bvec, E, c, m4, a0);

    // grid fixed so that 2*nwaves (=16384) is a multiple of NUM_F -> f constant
    const int block = 256;                        // 4 waves/block
    const int grid  = 2048;
    ft_main_kernel<<<grid, block, 0, stream>>>(
        x, W, c, m4, a0, gamma, beta, out, nrows);
}